// Round 5
// baseline (11278.574 us; speedup 1.0000x reference)
//
#include <hip/hip_runtime.h>

#define T_STEPS 4096
#define HD 2048
#define G4 8192
#define NWG 256
#define NTH 512
#define HSENT 0xFF80u
#define HSENT2 0xFF80FF80u

#define HB_OFF  131072                    // weights 128 KB, then h row 4 KB
#define P_OFF   (131072 + 4096)           // partials: 8 waves x 32 f32 = 1 KB
#define SMEM_BYTES (131072 + 4096 + 1024)

typedef __attribute__((ext_vector_type(8))) short bf16x8;
typedef __attribute__((ext_vector_type(4))) float f32x4;
typedef __attribute__((ext_vector_type(8))) unsigned short u16x8;
typedef __attribute__((ext_vector_type(2))) unsigned int u32x2;
typedef __attribute__((ext_vector_type(4))) unsigned int u32x4;

static __device__ __forceinline__ unsigned short f2bf(float f){
  union { float f; unsigned int u; } v; v.f = f;
  unsigned int r = (v.u + 0x7fffu + ((v.u >> 16) & 1u)) >> 16;
  return (unsigned short)r;
}
static __device__ __forceinline__ float bf2f(unsigned short s){
  union { unsigned int u; float f; } v; v.u = ((unsigned int)s) << 16;
  return v.f;
}

// uncached (coherence-point) 8B load — bypasses L1/L2, no fences needed
static __device__ __forceinline__ u32x2 ld2_uc(const unsigned int* p){
  u32x2 r;
  asm volatile("global_load_dwordx2 %0, %1, off sc0 sc1\n\ts_waitcnt vmcnt(0)"
               : "=v"(r) : "v"(p) : "memory");
  return r;
}
// write-through 16B store (single publish per WG per step)
static __device__ __forceinline__ void st4_uc(unsigned int* p, u32x4 v){
  asm volatile("global_store_dwordx4 %0, %1, off sc0 sc1" :: "v"(p), "v"(v) : "memory");
}

// ---------------- init: bias fuse + h0 zeros + sentinel rows (bf16) ----------------
__global__ void init_kernel(const float* __restrict__ b_ih, const float* __restrict__ b_hh,
                            float* __restrict__ bias, unsigned int* __restrict__ Hb32){
  int i = blockIdx.x*blockDim.x + threadIdx.x;
  int stride = gridDim.x*blockDim.x;
  const int HB_U32 = (T_STEPS+1)*HD/2;
  const int NTOT = G4 + HB_U32;
  for (int idx = i; idx < NTOT; idx += stride){
    if (idx < G4) bias[idx] = b_ih[idx] + b_hh[idx];
    else {
      int j = idx - G4;
      Hb32[j] = (j < HD/2) ? 0u : HSENT2;   // row 0 = bf16 zeros, rest sentinel
    }
  }
}

// ---------------- phase 1: XP = x @ W_ih^T + (b_ih+b_hh), bf16 out ----------------
__global__ __launch_bounds__(256) void gemm_xp(const float* __restrict__ X,
                                               const float* __restrict__ W,
                                               const float* __restrict__ bias,
                                               unsigned short* __restrict__ XP){
  __shared__ __align__(16) unsigned short As[128][40];
  __shared__ __align__(16) unsigned short Bs[128][40];
  const int tid = threadIdx.x;
  const int bx = blockIdx.x & 63;
  const int by = blockIdx.x >> 6;
  const int row0 = by*128, col0 = bx*128;
  const int l = tid & 63, w = tid >> 6;
  const int wrow = (w>>1)*64, wcol = (w&1)*64;
  const int lr = l & 15, lk = l >> 4;

  f32x4 acc[4][4];
  #pragma unroll
  for (int mi=0; mi<4; mi++)
    #pragma unroll
    for (int ni=0; ni<4; ni++)
      acc[mi][ni] = (f32x4){0.f,0.f,0.f,0.f};

  const int sr = tid >> 1;
  const int sh = (tid & 1) * 16;
  const float* xb = X + (size_t)(row0+sr)*2048 + sh;
  const float* wb = W + (size_t)(col0+sr)*2048 + sh;

  for (int k0 = 0; k0 < 2048; k0 += 32){
    __syncthreads();
    u16x8 va[2], vb[2];
    #pragma unroll
    for (int q=0; q<2; q++){
      float4 u = *(const float4*)(xb + k0 + q*8);
      float4 v = *(const float4*)(xb + k0 + q*8 + 4);
      u16x8 t;
      t[0]=f2bf(u.x); t[1]=f2bf(u.y); t[2]=f2bf(u.z); t[3]=f2bf(u.w);
      t[4]=f2bf(v.x); t[5]=f2bf(v.y); t[6]=f2bf(v.z); t[7]=f2bf(v.w);
      va[q]=t;
      float4 p = *(const float4*)(wb + k0 + q*8);
      float4 r = *(const float4*)(wb + k0 + q*8 + 4);
      u16x8 s;
      s[0]=f2bf(p.x); s[1]=f2bf(p.y); s[2]=f2bf(p.z); s[3]=f2bf(p.w);
      s[4]=f2bf(r.x); s[5]=f2bf(r.y); s[6]=f2bf(r.z); s[7]=f2bf(r.w);
      vb[q]=s;
    }
    *(u16x8*)&As[sr][sh]   = va[0];
    *(u16x8*)&As[sr][sh+8] = va[1];
    *(u16x8*)&Bs[sr][sh]   = vb[0];
    *(u16x8*)&Bs[sr][sh+8] = vb[1];
    __syncthreads();

    bf16x8 af[4], bfr[4];
    #pragma unroll
    for (int mi=0; mi<4; mi++) af[mi]  = *(const bf16x8*)&As[wrow+mi*16+lr][lk*8];
    #pragma unroll
    for (int ni=0; ni<4; ni++) bfr[ni] = *(const bf16x8*)&Bs[wcol+ni*16+lr][lk*8];
    #pragma unroll
    for (int mi=0; mi<4; mi++)
      #pragma unroll
      for (int ni=0; ni<4; ni++)
        acc[mi][ni] = __builtin_amdgcn_mfma_f32_16x16x32_bf16(af[mi], bfr[ni], acc[mi][ni], 0,0,0);
  }

  #pragma unroll
  for (int ni=0; ni<4; ni++){
    const int jc = col0 + wcol + ni*16 + lr;
    const float bv = bias[jc];
    #pragma unroll
    for (int mi=0; mi<4; mi++){
      const int tr0 = row0 + wrow + mi*16 + lk*4;
      #pragma unroll
      for (int r=0; r<4; r++)
        XP[(size_t)(tr0+r)*G4 + jc] = f2bf(acc[mi][ni][r] + bv);
    }
  }
}

// ---------------- phase 2: persistent LSTM recurrence (MFMA, 8 waves) ----------------
// 256 WGs x 512 thr (8 waves). WG g owns h-dims [8g,8g+8) = 32 gate rows
// rr = gate*8+dd. gates(1x32) = h(1x2048) @ W^T via mfma_f32_16x16x32_bf16:
//   wave w covers K-slice [w*256, +256): kt=0..7 sub-slices x 2 col-tiles
//   = 16 MFMAs (two independent accumulator chains).
//   A-frag: same-address LDS broadcast of h (all 16 rows = same GEMV).
// Weights in LDS as pre-swizzled B-fragments (128 KB), re-read each step;
// the 16 ds_read_b128 are issued BEFORE the poll (lgkmcnt independent of
// vmcnt) so their latency hides under poll detect.
// Sync: bf16 sentinel (0xFF80=-inf, unreachable since |h|<1) poll on
// uncached dwordx2; publish = ONE write-through dwordx4 per WG per step
// (lanes 0-7 pack via shuffles). No fences, no atomics.
__global__ __launch_bounds__(NTH, 1) void recur(const unsigned short* __restrict__ XP,
                                                const float* __restrict__ Whh,
                                                unsigned short* __restrict__ Hbuf){
  extern __shared__ char smem[];
  float* part = (float*)(smem + P_OFF);
  char*  hb   = smem + HB_OFF;
  const int g = blockIdx.x;
  const int tid = threadIdx.x;
  const int l = tid & 63, w = tid >> 6;

  // ---- stage weights as pre-swizzled MFMA B-fragments ----
  // block idx = w*16 + n*8 + kt; lane l holds B[col=n*16+(l&15)][k=(l>>4)*8..+8]
  #pragma unroll
  for (int n=0; n<2; n++)
    #pragma unroll
    for (int kt=0; kt<8; kt++){
      const int rr = n*16 + (l & 15);
      const size_t jrow = (size_t)(rr>>3)*HD + (size_t)g*8 + (rr&7);
      const int k = w*256 + kt*32 + (l>>4)*8;
      const float* wp = Whh + jrow*HD + k;
      float4 fa = *(const float4*)wp;
      float4 fb = *(const float4*)(wp + 4);
      uint4 pk;
      pk.x = ((unsigned)f2bf(fa.y)<<16) | f2bf(fa.x);
      pk.y = ((unsigned)f2bf(fa.w)<<16) | f2bf(fa.z);
      pk.z = ((unsigned)f2bf(fb.y)<<16) | f2bf(fb.x);
      pk.w = ((unsigned)f2bf(fb.w)<<16) | f2bf(fb.z);
      *(uint4*)(smem + (size_t)(((w*16 + n*8 + kt)*64 + l)*16)) = pk;
    }
  __syncthreads();

  float c_reg = 0.f;   // cell state (lanes tid<8)

  for (int t=0; t<T_STEPS; ++t){
    // XP slice for cell lanes (cached, independent of h)
    float xpv0=0.f, xpv1=0.f, xpv2=0.f, xpv3=0.f;
    if (tid < 8){
      const unsigned short* xp = XP + (size_t)t*G4 + (size_t)g*8 + tid;
      xpv0 = bf2f(xp[0]);
      xpv1 = bf2f(xp[HD]);
      xpv2 = bf2f(xp[2*HD]);
      xpv3 = bf2f(xp[3*HD]);
    }
    // B-fragments: loop-invariant LDS reads issued before the poll
    bf16x8 bfr0[8], bfr1[8];
    #pragma unroll
    for (int kt=0; kt<8; kt++){
      bfr0[kt] = *(const bf16x8*)(smem + (size_t)(((w*16 +     kt)*64 + l)*16));
      bfr1[kt] = *(const bf16x8*)(smem + (size_t)(((w*16 + 8 + kt)*64 + l)*16));
    }

    // spin-wait on own 8B (4 bf16) of h[t-1] (row t; row 0 = zeros)
    u32x2 hv;
    {
      const unsigned int* hp = (const unsigned int*)(Hbuf + (size_t)t*HD) + tid*2;
      do { hv = ld2_uc(hp); }
      while ((hv[0] & 0xFFFFu) == HSENT || (hv[0] >> 16) == HSENT ||
             (hv[1] & 0xFFFFu) == HSENT || (hv[1] >> 16) == HSENT);
    }
    *(u32x2*)(hb + tid*8) = hv;
    __syncthreads();

    // A-fragments: broadcast h (same addr within each 16-lane group)
    bf16x8 af[8];
    #pragma unroll
    for (int kt=0; kt<8; kt++)
      af[kt] = *(const bf16x8*)(hb + (w*512 + kt*64 + (l>>4)*16));

    f32x4 acc0 = (f32x4){0.f,0.f,0.f,0.f};
    f32x4 acc1 = (f32x4){0.f,0.f,0.f,0.f};
    #pragma unroll
    for (int kt=0; kt<8; kt++){
      acc0 = __builtin_amdgcn_mfma_f32_16x16x32_bf16(af[kt], bfr0[kt], acc0, 0,0,0);
      acc1 = __builtin_amdgcn_mfma_f32_16x16x32_bf16(af[kt], bfr1[kt], acc1, 0,0,0);
    }
    // D row 0 = lanes 0..15, reg 0
    if (l < 16){
      part[w*32 + l]      = acc0[0];
      part[w*32 + 16 + l] = acc1[0];
    }
    __syncthreads();

    // wave 0: reduce 8 partials per gate-row, cell update, packed publish
    if (w == 0 && l < 32){
      float tot = 0.f;
      #pragma unroll
      for (int q=0; q<8; q++) tot += part[q*32 + l];
      float fg = __shfl_down(tot, 8, 64);
      float gg = __shfl_down(tot, 16, 64);
      float og = __shfl_down(tot, 24, 64);
      if (l < 8){
        float ipre = tot + xpv0;
        float fpre = fg  + xpv1;
        float gpre = gg  + xpv2;
        float opre = og  + xpv3;
        float iv = 1.f/(1.f + __expf(-ipre));
        float fv = 1.f/(1.f + __expf(-fpre));
        float e2 = __expf(-2.f*gpre);
        float gv = (1.f - e2)/(1.f + e2);
        float ov = 1.f/(1.f + __expf(-opre));
        c_reg = fv*c_reg + iv*gv;
        float e2c = __expf(-2.f*c_reg);
        float th = (1.f - e2c)/(1.f + e2c);
        // pack 8 bf16 into one dwordx4 on lane 0, single publish store
        unsigned v = f2bf(ov*th);
        unsigned p1 = (unsigned)__shfl_xor((int)v, 1, 64);
        unsigned d01 = (v & 0xFFFFu) | (p1 << 16);        // valid on even lanes
        unsigned d23 = (unsigned)__shfl_xor((int)d01, 2, 64);
        unsigned d45 = (unsigned)__shfl_xor((int)d01, 4, 64);
        unsigned d67 = (unsigned)__shfl_xor((int)d23, 4, 64);
        if (l == 0){
          u32x4 pk = (u32x4){d01, d23, d45, d67};
          st4_uc((unsigned int*)(Hbuf + (size_t)(t+1)*HD + (size_t)g*8), pk);
        }
      }
    }
  }
}

// ---------------- phase 3: y[t] = h_t . W_out + b_out (h is bf16) ----------------
__global__ __launch_bounds__(256) void out_gemv(const unsigned short* __restrict__ Hbuf,
                                                const float* __restrict__ Wout,
                                                const float* __restrict__ bout,
                                                float* __restrict__ y){
  const int t = blockIdx.x;
  const int tid = threadIdx.x;
  u16x8 hv = *(const u16x8*)(Hbuf + (size_t)(t+1)*HD + tid*8);
  float4 w0 = *(const float4*)(Wout + tid*8);
  float4 w1 = *(const float4*)(Wout + tid*8 + 4);
  float s = bf2f(hv[0])*w0.x + bf2f(hv[1])*w0.y + bf2f(hv[2])*w0.z + bf2f(hv[3])*w0.w
          + bf2f(hv[4])*w1.x + bf2f(hv[5])*w1.y + bf2f(hv[6])*w1.z + bf2f(hv[7])*w1.w;
  #pragma unroll
  for (int off=32; off; off>>=1) s += __shfl_xor(s, off, 64);
  __shared__ float ps[4];
  if ((tid & 63) == 0) ps[tid>>6] = s;
  __syncthreads();
  if (tid == 0) y[t] = ps[0]+ps[1]+ps[2]+ps[3] + bout[0];
}

extern "C" void kernel_launch(void* const* d_in, const int* in_sizes, int n_in,
                              void* d_out, int out_size, void* d_ws, size_t ws_size,
                              hipStream_t stream) {
  const float* x    = (const float*)d_in[0];
  const float* Wih  = (const float*)d_in[1];
  const float* Whh  = (const float*)d_in[2];
  const float* b_ih = (const float*)d_in[3];
  const float* b_hh = (const float*)d_in[4];
  const float* Wout = (const float*)d_in[5];
  const float* bout = (const float*)d_in[6];
  float* y = (float*)d_out;

  char* ws = (char*)d_ws;
  unsigned short* XP   = (unsigned short*)(ws);               // 4096*8192*2   = 67108864
  unsigned short* Hbuf = (unsigned short*)(ws + 67108864);    // 4097*2048*2   = 16781312
  float* bias          = (float*)(ws + 83890176);             // 8192*4        = 32768

  init_kernel<<<2048, 256, 0, stream>>>(b_ih, b_hh, bias, (unsigned int*)Hbuf);
  gemm_xp<<<2048, 256, 0, stream>>>(x, Wih, bias, XP);

  hipFuncSetAttribute((const void*)recur,
                      hipFuncAttributeMaxDynamicSharedMemorySize, SMEM_BYTES);
  void* args[] = {(void*)&XP, (void*)&Whh, (void*)&Hbuf};
  hipLaunchCooperativeKernel((void*)recur, dim3(NWG), dim3(NTH), args,
                             SMEM_BYTES, stream);

  out_gemv<<<T_STEPS, 256, 0, stream>>>(Hbuf, Wout, bout, y);
}

// Round 6
// 11135.139 us; speedup vs baseline: 1.0129x; 1.0129x over previous
//
#include <hip/hip_runtime.h>

#define T_STEPS 4096
#define HD 2048
#define G4 8192
#define NWG 256
#define NTH 512
#define HSENT2 0xFF80FF80u

typedef __attribute__((ext_vector_type(8))) short bf16x8;
typedef __attribute__((ext_vector_type(4))) float f32x4;
typedef __attribute__((ext_vector_type(8))) unsigned short u16x8;
typedef __attribute__((ext_vector_type(2))) unsigned int u32x2;
typedef __attribute__((ext_vector_type(4))) unsigned int u32x4;

static __device__ __forceinline__ unsigned short f2bf(float f){
  union { float f; unsigned int u; } v; v.f = f;
  unsigned int r = (v.u + 0x7fffu + ((v.u >> 16) & 1u)) >> 16;
  return (unsigned short)r;
}
static __device__ __forceinline__ float bf2f(unsigned short s){
  union { unsigned int u; float f; } v; v.u = ((unsigned int)s) << 16;
  return v.f;
}

// uncached (coherence-point) 8B load — bypasses L1/L2
static __device__ __forceinline__ u32x2 ld2_uc(const unsigned int* p){
  u32x2 r;
  asm volatile("global_load_dwordx2 %0, %1, off sc0 sc1\n\ts_waitcnt vmcnt(0)"
               : "=v"(r) : "v"(p) : "memory");
  return r;
}
// write-through 16B store (single publish per WG per step)
static __device__ __forceinline__ void st4_uc(unsigned int* p, u32x4 v){
  asm volatile("global_store_dwordx4 %0, %1, off sc0 sc1" :: "v"(p), "v"(v) : "memory");
}

// ---------------- init: bias fuse + h0 zeros + sentinel rows (bf16) ----------------
__global__ void init_kernel(const float* __restrict__ b_ih, const float* __restrict__ b_hh,
                            float* __restrict__ bias, unsigned int* __restrict__ Hb32){
  int i = blockIdx.x*blockDim.x + threadIdx.x;
  int stride = gridDim.x*blockDim.x;
  const int HB_U32 = (T_STEPS+1)*HD/2;
  const int NTOT = G4 + HB_U32;
  for (int idx = i; idx < NTOT; idx += stride){
    if (idx < G4) bias[idx] = b_ih[idx] + b_hh[idx];
    else {
      int j = idx - G4;
      Hb32[j] = (j < HD/2) ? 0u : HSENT2;   // row 0 = bf16 zeros, rest sentinel
    }
  }
}

// ---------------- phase 1: XP = x @ W_ih^T + (b_ih+b_hh), bf16 out ----------------
__global__ __launch_bounds__(256) void gemm_xp(const float* __restrict__ X,
                                               const float* __restrict__ W,
                                               const float* __restrict__ bias,
                                               unsigned short* __restrict__ XP){
  __shared__ __align__(16) unsigned short As[128][40];
  __shared__ __align__(16) unsigned short Bs[128][40];
  const int tid = threadIdx.x;
  const int bx = blockIdx.x & 63;
  const int by = blockIdx.x >> 6;
  const int row0 = by*128, col0 = bx*128;
  const int l = tid & 63, w = tid >> 6;
  const int wrow = (w>>1)*64, wcol = (w&1)*64;
  const int lr = l & 15, lk = l >> 4;

  f32x4 acc[4][4];
  #pragma unroll
  for (int mi=0; mi<4; mi++)
    #pragma unroll
    for (int ni=0; ni<4; ni++)
      acc[mi][ni] = (f32x4){0.f,0.f,0.f,0.f};

  const int sr = tid >> 1;
  const int sh = (tid & 1) * 16;
  const float* xb = X + (size_t)(row0+sr)*2048 + sh;
  const float* wb = W + (size_t)(col0+sr)*2048 + sh;

  for (int k0 = 0; k0 < 2048; k0 += 32){
    __syncthreads();
    u16x8 va[2], vb[2];
    #pragma unroll
    for (int q=0; q<2; q++){
      float4 u = *(const float4*)(xb + k0 + q*8);
      float4 v = *(const float4*)(xb + k0 + q*8 + 4);
      u16x8 t;
      t[0]=f2bf(u.x); t[1]=f2bf(u.y); t[2]=f2bf(u.z); t[3]=f2bf(u.w);
      t[4]=f2bf(v.x); t[5]=f2bf(v.y); t[6]=f2bf(v.z); t[7]=f2bf(v.w);
      va[q]=t;
      float4 p = *(const float4*)(wb + k0 + q*8);
      float4 r = *(const float4*)(wb + k0 + q*8 + 4);
      u16x8 s;
      s[0]=f2bf(p.x); s[1]=f2bf(p.y); s[2]=f2bf(p.z); s[3]=f2bf(p.w);
      s[4]=f2bf(r.x); s[5]=f2bf(r.y); s[6]=f2bf(r.z); s[7]=f2bf(r.w);
      vb[q]=s;
    }
    *(u16x8*)&As[sr][sh]   = va[0];
    *(u16x8*)&As[sr][sh+8] = va[1];
    *(u16x8*)&Bs[sr][sh]   = vb[0];
    *(u16x8*)&Bs[sr][sh+8] = vb[1];
    __syncthreads();

    bf16x8 af[4], bfr[4];
    #pragma unroll
    for (int mi=0; mi<4; mi++) af[mi]  = *(const bf16x8*)&As[wrow+mi*16+lr][lk*8];
    #pragma unroll
    for (int ni=0; ni<4; ni++) bfr[ni] = *(const bf16x8*)&Bs[wcol+ni*16+lr][lk*8];
    #pragma unroll
    for (int mi=0; mi<4; mi++)
      #pragma unroll
      for (int ni=0; ni<4; ni++)
        acc[mi][ni] = __builtin_amdgcn_mfma_f32_16x16x32_bf16(af[mi], bfr[ni], acc[mi][ni], 0,0,0);
  }

  #pragma unroll
  for (int ni=0; ni<4; ni++){
    const int jc = col0 + wcol + ni*16 + lr;
    const float bv = bias[jc];
    #pragma unroll
    for (int mi=0; mi<4; mi++){
      const int tr0 = row0 + wrow + mi*16 + lk*4;
      #pragma unroll
      for (int r=0; r<4; r++)
        XP[(size_t)(tr0+r)*G4 + jc] = f2bf(acc[mi][ni][r] + bv);
    }
  }
}

// ---------------- phase 2: persistent LSTM recurrence (MFMA, 8 waves) ----------------
// 256 WGs x 512 thr. WG g owns h-dims [8g,8g+8) = 32 gate rows (rr=gate*8+dd).
// Weights as MFMA B-fragments in REGISTERS (16 x bf16x8 = 64 VGPR; cap 256 via
// __launch_bounds__(512,1) — R1's spill was the (1024,4) 128-VGPR cap).
// Per step, wave w:
//   - polls ONLY its own K-span h[w*256 .. +256) (its 32 producers) via
//     uncached dwordx2 sentinel loop (0xFF80 = bf16 -inf, unreachable)
//   - writes span to its private LDS region, reads A-frags (same-wave
//     lgkmcnt ordering, NO barrier) -> 16 MFMAs (2 col-tiles x 8 kt)
//   - writes 32 partials, ONE barrier, wave 0 reduces + cell + 1 publish.
// part[] double-buffered (t&1) so waves may run a step ahead of the reducer.
// Early spans compute while stragglers are in flight; critical path after the
// last producer = detect + 8 MFMA chain + barrier + reduce + cell + store.
__global__ __launch_bounds__(NTH, 1) void recur(const unsigned short* __restrict__ XP,
                                                const float* __restrict__ Whh,
                                                unsigned short* __restrict__ Hbuf){
  __shared__ __align__(16) char hb[4096];     // 8 waves x 512 B span
  __shared__ float part[2][256];              // [parity][wave*32 + row]
  const int g = blockIdx.x;
  const int tid = threadIdx.x;
  const int l = tid & 63, w = tid >> 6;
  if (w == 0) __builtin_amdgcn_s_setprio(1);  // reducer wave = critical path

  // ---- B-fragments into registers (one-time global load + bf16 pack) ----
  // bw[n][kt]: lane l holds B[col=n*16+(l&15)][k=w*256+kt*32+(l>>4)*8 .. +8]
  bf16x8 bw0[8], bw1[8];
  #pragma unroll
  for (int n=0; n<2; n++)
    #pragma unroll
    for (int kt=0; kt<8; kt++){
      const int rr = n*16 + (l & 15);
      const size_t jrow = (size_t)(rr>>3)*HD + (size_t)g*8 + (rr&7);
      const int k = w*256 + kt*32 + (l>>4)*8;
      const float* wp = Whh + jrow*HD + k;
      float4 fa = *(const float4*)wp;
      float4 fb = *(const float4*)(wp + 4);
      uint4 pk;
      pk.x = ((unsigned)f2bf(fa.y)<<16) | f2bf(fa.x);
      pk.y = ((unsigned)f2bf(fa.w)<<16) | f2bf(fa.z);
      pk.z = ((unsigned)f2bf(fb.y)<<16) | f2bf(fb.x);
      pk.w = ((unsigned)f2bf(fb.w)<<16) | f2bf(fb.z);
      bf16x8 fr;
      *(uint4*)&fr = pk;
      asm volatile("" : "+v"(fr));            // pin against rematerialization
      if (n == 0) bw0[kt] = fr; else bw1[kt] = fr;
    }

  float c_reg = 0.f;   // cell state (lanes tid<8)
  // XP slice for step 0 (cell lanes)
  float xpv0=0.f, xpv1=0.f, xpv2=0.f, xpv3=0.f;
  if (tid < 8){
    const unsigned short* xp = XP + (size_t)g*8 + tid;
    xpv0 = bf2f(xp[0]);
    xpv1 = bf2f(xp[HD]);
    xpv2 = bf2f(xp[2*HD]);
    xpv3 = bf2f(xp[3*HD]);
  }

  for (int t=0; t<T_STEPS; ++t){
    // ---- poll own span of h[t-1] (row t; row 0 = zeros) ----
    u32x2 hv;
    {
      const unsigned int* hp = (const unsigned int*)(Hbuf + (size_t)t*HD) + w*128 + l*2;
      do { hv = ld2_uc(hp); }
      while (hv[0] == HSENT2 || hv[1] == HSENT2);
    }
    *(u32x2*)(hb + w*512 + l*8) = hv;
    // A-frags from own span (same-wave ds ordering, no barrier needed)
    bf16x8 af[8];
    #pragma unroll
    for (int kt=0; kt<8; kt++)
      af[kt] = *(const bf16x8*)(hb + w*512 + kt*64 + (l>>4)*16);

    f32x4 acc0 = (f32x4){0.f,0.f,0.f,0.f};
    f32x4 acc1 = (f32x4){0.f,0.f,0.f,0.f};
    #pragma unroll
    for (int kt=0; kt<8; kt++){
      acc0 = __builtin_amdgcn_mfma_f32_16x16x32_bf16(af[kt], bw0[kt], acc0, 0,0,0);
      acc1 = __builtin_amdgcn_mfma_f32_16x16x32_bf16(af[kt], bw1[kt], acc1, 0,0,0);
    }
    // D row 0 = lanes 0..15, reg 0
    if (l < 16){
      part[t&1][w*32 + l]      = acc0[0];
      part[t&1][w*32 + 16 + l] = acc1[0];
    }
    __syncthreads();

    // wave 0: reduce 8 partials per gate-row, cell update, packed publish
    if (w == 0 && l < 32){
      float tot = 0.f;
      #pragma unroll
      for (int q=0; q<8; q++) tot += part[t&1][q*32 + l];
      float fg = __shfl_down(tot, 8, 64);
      float gg = __shfl_down(tot, 16, 64);
      float og = __shfl_down(tot, 24, 64);
      if (l < 8){
        float ipre = tot + xpv0;
        float fpre = fg  + xpv1;
        float gpre = gg  + xpv2;
        float opre = og  + xpv3;
        float iv = 1.f/(1.f + __expf(-ipre));
        float fv = 1.f/(1.f + __expf(-fpre));
        float e2 = __expf(-2.f*gpre);
        float gv = (1.f - e2)/(1.f + e2);
        float ov = 1.f/(1.f + __expf(-opre));
        c_reg = fv*c_reg + iv*gv;
        float e2c = __expf(-2.f*c_reg);
        float th = (1.f - e2c)/(1.f + e2c);
        unsigned v = f2bf(ov*th);
        unsigned p1 = (unsigned)__shfl_xor((int)v, 1, 64);
        unsigned d01 = (v & 0xFFFFu) | (p1 << 16);
        unsigned d23 = (unsigned)__shfl_xor((int)d01, 2, 64);
        unsigned d45 = (unsigned)__shfl_xor((int)d01, 4, 64);
        unsigned d67 = (unsigned)__shfl_xor((int)d23, 4, 64);
        if (l == 0){
          u32x4 pk = (u32x4){d01, d23, d45, d67};
          st4_uc((unsigned int*)(Hbuf + (size_t)(t+1)*HD + (size_t)g*8), pk);
        }
      }
    }
    // preload next step's XP (a full sync-RT of slack before its use)
    if (tid < 8){
      const int tn = (t+1 < T_STEPS) ? t+1 : t;
      const unsigned short* xp = XP + (size_t)tn*G4 + (size_t)g*8 + tid;
      xpv0 = bf2f(xp[0]);
      xpv1 = bf2f(xp[HD]);
      xpv2 = bf2f(xp[2*HD]);
      xpv3 = bf2f(xp[3*HD]);
    }
  }
}

// ---------------- phase 3: y[t] = h_t . W_out + b_out (h is bf16) ----------------
__global__ __launch_bounds__(256) void out_gemv(const unsigned short* __restrict__ Hbuf,
                                                const float* __restrict__ Wout,
                                                const float* __restrict__ bout,
                                                float* __restrict__ y){
  const int t = blockIdx.x;
  const int tid = threadIdx.x;
  u16x8 hv = *(const u16x8*)(Hbuf + (size_t)(t+1)*HD + tid*8);
  float4 w0 = *(const float4*)(Wout + tid*8);
  float4 w1 = *(const float4*)(Wout + tid*8 + 4);
  float s = bf2f(hv[0])*w0.x + bf2f(hv[1])*w0.y + bf2f(hv[2])*w0.z + bf2f(hv[3])*w0.w
          + bf2f(hv[4])*w1.x + bf2f(hv[5])*w1.y + bf2f(hv[6])*w1.z + bf2f(hv[7])*w1.w;
  #pragma unroll
  for (int off=32; off; off>>=1) s += __shfl_xor(s, off, 64);
  __shared__ float ps[4];
  if ((tid & 63) == 0) ps[tid>>6] = s;
  __syncthreads();
  if (tid == 0) y[t] = ps[0]+ps[1]+ps[2]+ps[3] + bout[0];
}

extern "C" void kernel_launch(void* const* d_in, const int* in_sizes, int n_in,
                              void* d_out, int out_size, void* d_ws, size_t ws_size,
                              hipStream_t stream) {
  const float* x    = (const float*)d_in[0];
  const float* Wih  = (const float*)d_in[1];
  const float* Whh  = (const float*)d_in[2];
  const float* b_ih = (const float*)d_in[3];
  const float* b_hh = (const float*)d_in[4];
  const float* Wout = (const float*)d_in[5];
  const float* bout = (const float*)d_in[6];
  float* y = (float*)d_out;

  char* ws = (char*)d_ws;
  unsigned short* XP   = (unsigned short*)(ws);               // 4096*8192*2   = 67108864
  unsigned short* Hbuf = (unsigned short*)(ws + 67108864);    // 4097*2048*2   = 16781312
  float* bias          = (float*)(ws + 83890176);             // 8192*4        = 32768

  init_kernel<<<2048, 256, 0, stream>>>(b_ih, b_hh, bias, (unsigned int*)Hbuf);
  gemm_xp<<<2048, 256, 0, stream>>>(x, Wih, bias, XP);

  void* args[] = {(void*)&XP, (void*)&Whh, (void*)&Hbuf};
  hipLaunchCooperativeKernel((void*)recur, dim3(NWG), dim3(NTH), args, 0, stream);

  out_gemv<<<T_STEPS, 256, 0, stream>>>(Hbuf, Wout, bout, y);
}